// Round 2
// 389.874 us; speedup vs baseline: 1.0370x; 1.0370x over previous
//
#include <hip/hip_runtime.h>
#include <cstddef>
#include <math.h>

// Problem constants (match reference)
#define S_TOK 4096
#define MDIM  2048
#define NE    32
#define CAP   256     // ceil(4096/32 * 1.0 * 2) = 256
#define TPB   256
#define TOKB  4       // tokens per block in gating kernel

#define OUT_MAIN (2 * S_TOK * NE * CAP)   // 67,108,864 floats before the tail

// native 4-float vector for __builtin_nontemporal_store (HIP's float4 is a
// class type the builtin rejects)
typedef float f32x4 __attribute__((ext_vector_type(4)));

// Atomic-free workspace: every field is written by an earlier kernel in the
// stream before it is read — NO zero-initialization pass needed.
struct Ws {
    int    e1a[S_TOK];        // top-1 expert per token
    int    e2a[S_TOK];        // top-2 expert per token
    float  g1a[S_TOK];        // softmax gate of top-1
    float  g2a[S_TOK];        // softmax gate of top-2
    float  v1a[S_TOK];        // raw top-1 logit
    float  v2a[S_TOK];        // raw top-2 logit
    int    keptA[S_TOK];      // init 0 by k_gate; set by k_capacity
    int    keptB[S_TOK];
    int    locA[S_TOK];       // init 0 by k_gate; set by k_capacity (kept only)
    int    locB[S_TOK];
    int    counts[NE];        // pre-capacity per-expert counts (k_capacity)
    double gate_sum[NE];      // per-expert softmax-gate column sums (k_capacity)
    float  gates[S_TOK * NE]; // full softmax gates matrix (k_gate)
};

// Kernel 1: logits (fp64 accumulate), softmax, top-2. One block = TOKB tokens.
// Thread (e=tid&31, seg=tid>>5) computes a 256-wide dot segment for expert e.
// Writes only per-token fields (each token owned by one lane) — no atomics.
// ALSO zero-fills this block's 256 KB slice of the output, replacing the old
// 170 us serial hipMemsetAsync (which was memsetting 4x the buffer: out_size
// is in BYTES — rocprof showed 1.074 GB written vs 268 MB needed). The zero
// stores overlap with the fp64 gating compute on the same dispatch.
__global__ __launch_bounds__(TPB) void k_gate(const float* __restrict__ x,
                                              const float* __restrict__ wg,
                                              Ws* __restrict__ ws,
                                              float* __restrict__ out) {
    __shared__ float4 xs4[TOKB * 512];           // 32 KB: x tile
    __shared__ double part[8][NE][TOKB];         // 8 KB: partial dots
    __shared__ float  logitsF[TOKB][NE];         // fp32 logits (match np values)

    const int tid = threadIdx.x;
    const int t0  = blockIdx.x * TOKB;

    // zero-fill: 1024 blocks x 16384 float4 = 67,108,864 floats (l_aux +
    // combine + dispatch). Nontemporal: pure streaming, don't pollute L2.
    {
        f32x4* o4 = reinterpret_cast<f32x4*>(out) + (size_t)blockIdx.x * 16384;
        const f32x4 z = {0.f, 0.f, 0.f, 0.f};
        #pragma unroll
        for (int k = 0; k < 64; ++k)
            __builtin_nontemporal_store(z, &o4[tid + k * TPB]);
        // 33-float tail (last dispatch_mask element + 32 exp_counts slots)
        if (blockIdx.x == 0 && tid < 33) out[OUT_MAIN + tid] = 0.f;
    }

    // stage x tile (coalesced float4)
    const float4* x4 = (const float4*)x;
    #pragma unroll
    for (int k = 0; k < (TOKB * 512) / TPB; ++k) {
        int idx = tid + k * TPB;
        xs4[idx] = x4[(size_t)t0 * 512 + idx];
    }
    __syncthreads();

    const int e   = tid & 31;
    const int seg = tid >> 5;   // 0..7
    double acc[TOKB];
    #pragma unroll
    for (int i = 0; i < TOKB; ++i) acc[i] = 0.0;

    const float4* wg4 = (const float4*)wg;       // wg row = 512 float4
    for (int j4 = 0; j4 < 64; ++j4) {
        float4 w = wg4[e * 512 + seg * 64 + j4];
        #pragma unroll
        for (int tt = 0; tt < TOKB; ++tt) {
            float4 xv = xs4[tt * 512 + seg * 64 + j4];   // LDS broadcast
            acc[tt] += (double)xv.x * w.x + (double)xv.y * w.y +
                       (double)xv.z * w.z + (double)xv.w * w.w;
        }
    }
    #pragma unroll
    for (int tt = 0; tt < TOKB; ++tt) part[seg][e][tt] = acc[tt];
    __syncthreads();

    if (tid < TOKB * 32) {
        int tok = tid >> 5;
        int ee  = tid & 31;
        double s = 0.0;
        #pragma unroll
        for (int sg = 0; sg < 8; ++sg) s += part[sg][ee][tok];
        logitsF[tok][ee] = (float)s;
    }
    __syncthreads();

    // Per-token top-2 + softmax. Each 32-lane half-wave handles one token.
    const int lane = tid & 63;
    const int half = lane >> 5;                  // 0/1
    const int grp  = (tid >> 6) * 2 + half;      // local token id
    const int le   = lane & 31;

    if (grp < TOKB) {
        float l = logitsF[grp][le];
        const int t = t0 + grp;

        // top-1 (ties -> lower index, matching jax.lax.top_k)
        float v1 = l; int e1 = le;
        #pragma unroll
        for (int m = 16; m >= 1; m >>= 1) {
            float ov = __shfl_xor(v1, m);
            int   oi = __shfl_xor(e1, m);
            if (ov > v1 || (ov == v1 && oi < e1)) { v1 = ov; e1 = oi; }
        }
        // top-2
        float v2 = (le == e1) ? -INFINITY : l;
        int   e2 = (le == e1) ? 0x7fffffff : le;
        #pragma unroll
        for (int m = 16; m >= 1; m >>= 1) {
            float ov = __shfl_xor(v2, m);
            int   oi = __shfl_xor(e2, m);
            if (ov > v2 || (ov == v2 && oi < e2)) { v2 = ov; e2 = oi; }
        }
        // softmax
        float p = expf(l - v1);
        float ssum = p;
        #pragma unroll
        for (int m = 16; m >= 1; m >>= 1) ssum += __shfl_xor(ssum, m);
        float gate = p / ssum;

        ws->gates[t * NE + le] = gate;           // full gates row (for gate_sum)

        float g1 = __shfl(gate, (half << 5) + e1);
        float g2 = __shfl(gate, (half << 5) + e2);

        if (le == 0) {
            ws->e1a[t] = e1;  ws->e2a[t] = e2;
            ws->g1a[t] = g1;  ws->g2a[t] = g2;
            ws->v1a[t] = v1;  ws->v2a[t] = v2;
            ws->keptA[t] = 0; ws->keptB[t] = 0;
            ws->locA[t]  = 0; ws->locB[t]  = 0;
        }
    }
}

// Kernel 2: per-expert capacity filter (exact dense-column rank semantics of
// top_k over topk_masked_gates.T, zeros included) + kept-token locations +
// counts + gate column sum. One block per expert; builds its own token list
// from e1a/e2a (order-independent math), so no global atomics anywhere.
__global__ __launch_bounds__(256) void k_capacity(Ws* __restrict__ ws) {
    __shared__ float vals[S_TOK];
    __shared__ int   toks[S_TOK];
    __shared__ unsigned char kept[S_TOK];
    __shared__ int   cnt;
    __shared__ double gred[4];

    const int e = blockIdx.x;
    const int tid = threadIdx.x;
    if (tid == 0) cnt = 0;
    __syncthreads();

    // build this expert's assigned-token list + column gate sum
    double gs = 0.0;
    for (int i = tid; i < S_TOK; i += 256) {
        gs += (double)ws->gates[i * NE + e];
        int a1 = ws->e1a[i];
        int a2 = ws->e2a[i];
        float v; bool hit = false;
        if (a1 == e)      { v = ws->v1a[i]; hit = true; }
        else if (a2 == e) { v = ws->v2a[i]; hit = true; }
        if (hit) {
            int k = atomicAdd(&cnt, 1);   // LDS atomic; list order irrelevant
            vals[k] = v; toks[k] = i;
        }
    }
    // block-reduce gate sum (4 waves)
    #pragma unroll
    for (int m = 32; m >= 1; m >>= 1) gs += __shfl_xor(gs, m);
    if ((tid & 63) == 0) gred[tid >> 6] = gs;
    __syncthreads();
    const int n = cnt;
    if (tid == 0) {
        ws->counts[e]   = n;
        ws->gate_sum[e] = gred[0] + gred[1] + gred[2] + gred[3];
    }

    for (int i = tid; i < n; i += 256) {
        float v = vals[i];
        int   t = toks[i];
        // dense rank: zeros (S-n of them) outrank v if v<0; ties -> lower index
        int rank = (v < 0.f) ? (S_TOK - n) : 0;
        int alt  = 0;
        for (int j = 0; j < n; ++j) {
            float vj = vals[j]; int tj = toks[j];
            rank += (vj > v || (vj == v && tj < t)) ? 1 : 0;
            alt  += (tj < t) ? 1 : 0;
        }
        if (v == 0.f) rank += t - alt;   // zeros tie with v==0 at lower index
        kept[i] = (rank < CAP) ? 1 : 0;
    }
    __syncthreads();

    for (int i = tid; i < n; i += 256) {
        if (!kept[i]) continue;
        int t = toks[i];
        int loc = 0;
        for (int j = 0; j < n; ++j) loc += (kept[j] && toks[j] < t) ? 1 : 0;
        if (ws->e1a[t] == e) { ws->keptA[t] = 1; ws->locA[t] = loc; }
        else                 { ws->keptB[t] = 1; ws->locB[t] = loc; }
    }
}

// Kernel 3: scatter nonzeros of combine_weights/dispatch_mask (blocks 0..15)
// + l_aux and exp_counts (block 16).
__global__ __launch_bounds__(256) void k_scatter_final(const Ws* __restrict__ ws,
                                                       float* __restrict__ out) {
    if (blockIdx.x < 16) {
        int t = blockIdx.x * 256 + threadIdx.x;
        int kA = ws->keptA[t], kB = ws->keptB[t];
        if (!(kA | kB)) return;
        float g1 = ws->g1a[t], g2 = ws->g2a[t];
        float d = (kA ? g1 : 0.f) + (kB ? g2 : 0.f);
        d = fmaxf(d, 1.1920929e-07f);            // finfo(f32).eps clip
        int loc = ws->locA[t] + ws->locB[t];     // unkept entries are 0
        if (loc >= CAP) return;                  // one_hot out-of-range -> zeros
        float* cw = out + 1;
        float* dm = out + 1 + (size_t)S_TOK * NE * CAP;
        if (kA) {
            size_t idx = (size_t)t * NE * CAP + (size_t)ws->e1a[t] * CAP + loc;
            cw[idx] = g1 / d; dm[idx] = 1.f;
        }
        if (kB) {
            size_t idx = (size_t)t * NE * CAP + (size_t)ws->e2a[t] * CAP + loc;
            cw[idx] = g2 / d; dm[idx] = 1.f;
        }
    } else {
        int tid = threadIdx.x;
        if (tid >= 64) return;
        double part = 0.0;
        if (tid < NE) {
            int c = ws->counts[tid];
            out[1 + 2 * (size_t)S_TOK * NE * CAP + tid] = (float)c;
            double me = ws->gate_sum[tid] / (double)S_TOK;
            double ce = (double)c / (double)S_TOK;
            part = me * ce;
        }
        #pragma unroll
        for (int m = 16; m >= 1; m >>= 1) part += __shfl_xor(part, m);
        if (tid == 0) out[0] = (float)(part * 16.0);   // mean*E*E/K = sum*16
    }
}

extern "C" void kernel_launch(void* const* d_in, const int* in_sizes, int n_in,
                              void* d_out, int out_size, void* d_ws, size_t ws_size,
                              hipStream_t stream) {
    const float* x  = (const float*)d_in[0];
    const float* wg = (const float*)d_in[1];
    float* out = (float*)d_out;
    Ws* ws = (Ws*)d_ws;

    // NOTE: no hipMemsetAsync — the old one wrote out_size*4 bytes (1.074 GB
    // per rocprof WRITE_SIZE; out_size is in bytes) = 4x the 268 MB output,
    // costing ~170 us serially at the write-BW ceiling. k_gate now zero-fills
    // the output fused with its compute.
    k_gate<<<S_TOK / TOKB, TPB, 0, stream>>>(x, wg, ws, out);
    k_capacity<<<NE, 256, 0, stream>>>(ws);
    k_scatter_final<<<17, 256, 0, stream>>>(ws, out);
}

// Round 3
// 389.719 us; speedup vs baseline: 1.0374x; 1.0004x over previous
//
#include <hip/hip_runtime.h>
#include <cstddef>
#include <math.h>

// Problem constants (match reference)
#define S_TOK 4096
#define MDIM  2048
#define NE    32
#define CAP   256     // ceil(4096/32 * 1.0 * 2) = 256
#define TPB   256
#define TOKB  4       // tokens per block in gating kernel

#define OUT_MAIN (2 * S_TOK * NE * CAP)   // 67,108,864 floats before the tail
#define O4_HALF  8388608                  // half the output in float4 units

// native 4-float vector for __builtin_nontemporal_store (HIP's float4 is a
// class type the builtin rejects)
typedef float f32x4 __attribute__((ext_vector_type(4)));

// Atomic-free workspace: every field is written by an earlier kernel in the
// stream before it is read — NO zero-initialization pass needed.
// NOTE: the 1 GiB / ~168 us fillBufferAligned dispatches in the profile are
// the HARNESS re-poisoning d_ws each iteration — fixed overhead, not ours.
struct Ws {
    int    e1a[S_TOK];        // top-1 expert per token
    int    e2a[S_TOK];        // top-2 expert per token
    float  g1a[S_TOK];        // softmax gate of top-1
    float  g2a[S_TOK];        // softmax gate of top-2
    float  v1a[S_TOK];        // raw top-1 logit
    float  v2a[S_TOK];        // raw top-2 logit
    int    keptA[S_TOK];      // init 0 by k_gate; set by k_capacity
    int    keptB[S_TOK];
    int    locA[S_TOK];       // init 0 by k_gate; set by k_capacity (kept only)
    int    locB[S_TOK];
    int    counts[NE];        // pre-capacity per-expert counts (k_capacity)
    double gate_sum[NE];      // per-expert softmax-gate column sums (k_capacity)
    float  gates[S_TOK * NE]; // full softmax gates matrix (k_gate)
};

// Kernel 1: logits (fp64 accumulate), softmax, top-2. One block = TOKB tokens.
// Thread (e=tid&31, seg=tid>>5) computes a 256-wide dot segment for expert e.
// Writes only per-token fields (each token owned by one lane) — no atomics.
// Also zero-fills the FIRST HALF of the output (134 MB), issued AFTER the
// wg-load compute loop: vmcnt is a FIFO, so stores issued before the loop
// force every compiler s_waitcnt on a wg load to first drain the fill —
// that stall cost ~29 us in the previous version. After the loop, the
// stores drain under the top-2/softmax epilogue and block retire.
__global__ __launch_bounds__(TPB) void k_gate(const float* __restrict__ x,
                                              const float* __restrict__ wg,
                                              Ws* __restrict__ ws,
                                              float* __restrict__ out) {
    __shared__ float4 xs4[TOKB * 512];           // 32 KB: x tile
    __shared__ double part[8][NE][TOKB];         // 8 KB: partial dots
    __shared__ float  logitsF[TOKB][NE];         // fp32 logits (match np values)

    const int tid = threadIdx.x;
    const int t0  = blockIdx.x * TOKB;

    // stage x tile (coalesced float4)
    const float4* x4 = (const float4*)x;
    #pragma unroll
    for (int k = 0; k < (TOKB * 512) / TPB; ++k) {
        int idx = tid + k * TPB;
        xs4[idx] = x4[(size_t)t0 * 512 + idx];
    }
    __syncthreads();

    const int e   = tid & 31;
    const int seg = tid >> 5;   // 0..7
    double acc[TOKB];
    #pragma unroll
    for (int i = 0; i < TOKB; ++i) acc[i] = 0.0;

    const float4* wg4 = (const float4*)wg;       // wg row = 512 float4
    for (int j4 = 0; j4 < 64; ++j4) {
        float4 w = wg4[e * 512 + seg * 64 + j4];
        #pragma unroll
        for (int tt = 0; tt < TOKB; ++tt) {
            float4 xv = xs4[tt * 512 + seg * 64 + j4];   // LDS broadcast
            acc[tt] += (double)xv.x * w.x + (double)xv.y * w.y +
                       (double)xv.z * w.z + (double)xv.w * w.w;
        }
    }

    // zero-fill first half: 1024 blocks x 8192 float4 = 8,388,608 float4.
    // Nontemporal streaming stores; all wg loads above are already consumed,
    // so these never sit ahead of a load in the vmcnt FIFO.
    {
        f32x4* o4 = reinterpret_cast<f32x4*>(out) + (size_t)blockIdx.x * 8192;
        const f32x4 z = {0.f, 0.f, 0.f, 0.f};
        #pragma unroll
        for (int k = 0; k < 32; ++k)
            __builtin_nontemporal_store(z, &o4[tid + k * TPB]);
        // 33-float tail (last dispatch_mask element + 32 exp_counts slots)
        if (blockIdx.x == 0 && tid < 33) out[OUT_MAIN + tid] = 0.f;
    }

    #pragma unroll
    for (int tt = 0; tt < TOKB; ++tt) part[seg][e][tt] = acc[tt];
    __syncthreads();

    if (tid < TOKB * 32) {
        int tok = tid >> 5;
        int ee  = tid & 31;
        double s = 0.0;
        #pragma unroll
        for (int sg = 0; sg < 8; ++sg) s += part[sg][ee][tok];
        logitsF[tok][ee] = (float)s;
    }
    __syncthreads();

    // Per-token top-2 + softmax. Each 32-lane half-wave handles one token.
    const int lane = tid & 63;
    const int half = lane >> 5;                  // 0/1
    const int grp  = (tid >> 6) * 2 + half;      // local token id
    const int le   = lane & 31;

    if (grp < TOKB) {
        float l = logitsF[grp][le];
        const int t = t0 + grp;

        // top-1 (ties -> lower index, matching jax.lax.top_k)
        float v1 = l; int e1 = le;
        #pragma unroll
        for (int m = 16; m >= 1; m >>= 1) {
            float ov = __shfl_xor(v1, m);
            int   oi = __shfl_xor(e1, m);
            if (ov > v1 || (ov == v1 && oi < e1)) { v1 = ov; e1 = oi; }
        }
        // top-2
        float v2 = (le == e1) ? -INFINITY : l;
        int   e2 = (le == e1) ? 0x7fffffff : le;
        #pragma unroll
        for (int m = 16; m >= 1; m >>= 1) {
            float ov = __shfl_xor(v2, m);
            int   oi = __shfl_xor(e2, m);
            if (ov > v2 || (ov == v2 && oi < e2)) { v2 = ov; e2 = oi; }
        }
        // softmax
        float p = expf(l - v1);
        float ssum = p;
        #pragma unroll
        for (int m = 16; m >= 1; m >>= 1) ssum += __shfl_xor(ssum, m);
        float gate = p / ssum;

        ws->gates[t * NE + le] = gate;           // full gates row (for gate_sum)

        float g1 = __shfl(gate, (half << 5) + e1);
        float g2 = __shfl(gate, (half << 5) + e2);

        if (le == 0) {
            ws->e1a[t] = e1;  ws->e2a[t] = e2;
            ws->g1a[t] = g1;  ws->g2a[t] = g2;
            ws->v1a[t] = v1;  ws->v2a[t] = v2;
            ws->keptA[t] = 0; ws->keptB[t] = 0;
            ws->locA[t]  = 0; ws->locB[t]  = 0;
        }
    }
}

// Kernel 2: per-expert capacity filter (exact dense-column rank semantics of
// top_k over topk_masked_gates.T, zeros included) + kept-token locations +
// counts + gate column sum. Blocks 0..31: one per expert; builds its own
// token list from e1a/e2a (order-independent math), so no global atomics.
// Blocks 32..543: pure zero-fill of the SECOND HALF of the output (134 MB) —
// the expert blocks use only 32 of 256 CUs, so the fill streams on the
// otherwise-idle CUs concurrently. Fill still fully precedes k_scatter.
__global__ __launch_bounds__(256) void k_capacity(Ws* __restrict__ ws,
                                                  float* __restrict__ out) {
    if (blockIdx.x >= NE) {
        const int fb = blockIdx.x - NE;          // 0..511
        f32x4* o4 = reinterpret_cast<f32x4*>(out) + O4_HALF + (size_t)fb * 16384;
        const f32x4 z = {0.f, 0.f, 0.f, 0.f};
        #pragma unroll
        for (int k = 0; k < 64; ++k)
            __builtin_nontemporal_store(z, &o4[threadIdx.x + k * 256]);
        return;
    }

    __shared__ float vals[S_TOK];
    __shared__ int   toks[S_TOK];
    __shared__ unsigned char kept[S_TOK];
    __shared__ int   cnt;
    __shared__ double gred[4];

    const int e = blockIdx.x;
    const int tid = threadIdx.x;
    if (tid == 0) cnt = 0;
    __syncthreads();

    // build this expert's assigned-token list + column gate sum
    double gs = 0.0;
    for (int i = tid; i < S_TOK; i += 256) {
        gs += (double)ws->gates[i * NE + e];
        int a1 = ws->e1a[i];
        int a2 = ws->e2a[i];
        float v; bool hit = false;
        if (a1 == e)      { v = ws->v1a[i]; hit = true; }
        else if (a2 == e) { v = ws->v2a[i]; hit = true; }
        if (hit) {
            int k = atomicAdd(&cnt, 1);   // LDS atomic; list order irrelevant
            vals[k] = v; toks[k] = i;
        }
    }
    // block-reduce gate sum (4 waves)
    #pragma unroll
    for (int m = 32; m >= 1; m >>= 1) gs += __shfl_xor(gs, m);
    if ((tid & 63) == 0) gred[tid >> 6] = gs;
    __syncthreads();
    const int n = cnt;
    if (tid == 0) {
        ws->counts[e]   = n;
        ws->gate_sum[e] = gred[0] + gred[1] + gred[2] + gred[3];
    }

    for (int i = tid; i < n; i += 256) {
        float v = vals[i];
        int   t = toks[i];
        // dense rank: zeros (S-n of them) outrank v if v<0; ties -> lower index
        int rank = (v < 0.f) ? (S_TOK - n) : 0;
        int alt  = 0;
        for (int j = 0; j < n; ++j) {
            float vj = vals[j]; int tj = toks[j];
            rank += (vj > v || (vj == v && tj < t)) ? 1 : 0;
            alt  += (tj < t) ? 1 : 0;
        }
        if (v == 0.f) rank += t - alt;   // zeros tie with v==0 at lower index
        kept[i] = (rank < CAP) ? 1 : 0;
    }
    __syncthreads();

    for (int i = tid; i < n; i += 256) {
        if (!kept[i]) continue;
        int t = toks[i];
        int loc = 0;
        for (int j = 0; j < n; ++j) loc += (kept[j] && toks[j] < t) ? 1 : 0;
        if (ws->e1a[t] == e) { ws->keptA[t] = 1; ws->locA[t] = loc; }
        else                 { ws->keptB[t] = 1; ws->locB[t] = loc; }
    }
}

// Kernel 3: scatter nonzeros of combine_weights/dispatch_mask (blocks 0..15)
// + l_aux and exp_counts (block 16).
__global__ __launch_bounds__(256) void k_scatter_final(const Ws* __restrict__ ws,
                                                       float* __restrict__ out) {
    if (blockIdx.x < 16) {
        int t = blockIdx.x * 256 + threadIdx.x;
        int kA = ws->keptA[t], kB = ws->keptB[t];
        if (!(kA | kB)) return;
        float g1 = ws->g1a[t], g2 = ws->g2a[t];
        float d = (kA ? g1 : 0.f) + (kB ? g2 : 0.f);
        d = fmaxf(d, 1.1920929e-07f);            // finfo(f32).eps clip
        int loc = ws->locA[t] + ws->locB[t];     // unkept entries are 0
        if (loc >= CAP) return;                  // one_hot out-of-range -> zeros
        float* cw = out + 1;
        float* dm = out + 1 + (size_t)S_TOK * NE * CAP;
        if (kA) {
            size_t idx = (size_t)t * NE * CAP + (size_t)ws->e1a[t] * CAP + loc;
            cw[idx] = g1 / d; dm[idx] = 1.f;
        }
        if (kB) {
            size_t idx = (size_t)t * NE * CAP + (size_t)ws->e2a[t] * CAP + loc;
            cw[idx] = g2 / d; dm[idx] = 1.f;
        }
    } else {
        int tid = threadIdx.x;
        if (tid >= 64) return;
        double part = 0.0;
        if (tid < NE) {
            int c = ws->counts[tid];
            out[1 + 2 * (size_t)S_TOK * NE * CAP + tid] = (float)c;
            double me = ws->gate_sum[tid] / (double)S_TOK;
            double ce = (double)c / (double)S_TOK;
            part = me * ce;
        }
        #pragma unroll
        for (int m = 16; m >= 1; m >>= 1) part += __shfl_xor(part, m);
        if (tid == 0) out[0] = (float)(part * 16.0);   // mean*E*E/K = sum*16
    }
}

extern "C" void kernel_launch(void* const* d_in, const int* in_sizes, int n_in,
                              void* d_out, int out_size, void* d_ws, size_t ws_size,
                              hipStream_t stream) {
    const float* x  = (const float*)d_in[0];
    const float* wg = (const float*)d_in[1];
    float* out = (float*)d_out;
    Ws* ws = (Ws*)d_ws;

    // Output zero-fill is split: first half fused into k_gate (post-compute,
    // no vmcnt interference), second half on k_capacity's 512 extra fill
    // blocks (overlapped with the 32 expert blocks on otherwise-idle CUs).
    k_gate<<<S_TOK / TOKB, TPB, 0, stream>>>(x, wg, ws, out);
    k_capacity<<<NE + 512, 256, 0, stream>>>(ws, out);
    k_scatter_final<<<17, 256, 0, stream>>>(ws, out);
}